// Round 1
// baseline (5932.592 us; speedup 1.0000x reference)
//
#include <hip/hip_runtime.h>

#define SEQ   200
#define BATCH 4096
#define EMB   100
#define HID   300
#define NH1   256
#define BM    16
#define UP    404   // u row stride (floats): 1616B, 16B-aligned, bank shift 20 -> conflict-free
#define H1P   260

__device__ __forceinline__ void fma4(float& acc, const float4 a, const float4 w) {
    acc += a.x * w.x;
    acc += a.y * w.y;
    acc += a.z * w.z;
    acc += a.w * w.w;
}

__global__ void __launch_bounds__(512)
rnn_fused(const int* __restrict__ x, const float* __restrict__ emb,
          const float* __restrict__ W_ih, const float* __restrict__ b_ih,
          const float* __restrict__ W_hh, const float* __restrict__ b_hh,
          const float* __restrict__ W1, const float* __restrict__ b1,
          const float* __restrict__ W2, const float* __restrict__ b2,
          float* __restrict__ out)
{
    __shared__ float u[BM][UP];     // [xe(100) | h(300)] per row
    __shared__ float h1s[BM][H1P];

    const int tid  = threadIdx.x;
    const int row0 = blockIdx.x * BM;

    // GEMM thread tile: 2 rows (q, q+8) x 5 cols
    const int q  = tid & 7;
    const int c  = tid >> 3;        // 0..63
    const int r0 = q, r1 = q + 8;

    // distribute 300 cols over 64 groups: first 44 get 5 cols, rest get 4
    const int jbase = (c < 44) ? (5 * c) : (220 + 4 * (c - 44));
    const int nc    = (c < 44) ? 5 : 4;
    int js[5];
#pragma unroll
    for (int s = 0; s < 5; ++s) {
        int j = jbase + s;
        js[s] = (j > HID - 1) ? (HID - 1) : j;   // clamped dup: computed, not written
    }

    float bias[5];
#pragma unroll
    for (int s = 0; s < 5; ++s) bias[s] = b_ih[js[s]] + b_hh[js[s]];

    // zero h region
    for (int i = tid; i < BM * UP; i += 512) ((float*)u)[i] = 0.0f;
    __syncthreads();

    // gather xe for t=0 (25 float4 per row, 32 threads per row)
    {
        const int gr = tid >> 5, gl = tid & 31;
        const int idx = x[row0 + gr];
        if (gl < EMB / 4)
            ((float4*)&u[gr][0])[gl] = ((const float4*)(emb + (size_t)idx * EMB))[gl];
    }
    __syncthreads();

    const float4* wih[5];
    const float4* whh[5];
#pragma unroll
    for (int s = 0; s < 5; ++s) {
        wih[s] = (const float4*)(W_ih + (size_t)js[s] * EMB);
        whh[s] = (const float4*)(W_hh + (size_t)js[s] * HID);
    }

    for (int t = 0; t < SEQ; ++t) {
        float a0[5], a1[5];
#pragma unroll
        for (int s = 0; s < 5; ++s) { a0[s] = bias[s]; a1[s] = bias[s]; }

        // xe part: K = 100
        {
            const float4* ua = (const float4*)&u[r0][0];
            const float4* ub = (const float4*)&u[r1][0];
            for (int kk = 0; kk < EMB / 4; ++kk) {
                const float4 a = ua[kk], b = ub[kk];
#pragma unroll
                for (int s = 0; s < 5; ++s) {
                    const float4 w = wih[s][kk];
                    fma4(a0[s], a, w);
                    fma4(a1[s], b, w);
                }
            }
        }
        // h part: K = 300
        {
            const float4* ua = (const float4*)&u[r0][EMB];
            const float4* ub = (const float4*)&u[r1][EMB];
            for (int kk = 0; kk < HID / 4; ++kk) {
                const float4 a = ua[kk], b = ub[kk];
#pragma unroll
                for (int s = 0; s < 5; ++s) {
                    const float4 w = whh[s][kk];
                    fma4(a0[s], a, w);
                    fma4(a1[s], b, w);
                }
            }
        }

        __syncthreads();   // all reads of u (h_t, xe_t) complete
#pragma unroll
        for (int s = 0; s < 5; ++s) {
            if (s < nc) {
                u[r0][EMB + js[s]] = tanhf(a0[s]);
                u[r1][EMB + js[s]] = tanhf(a1[s]);
            }
        }
        if (t + 1 < SEQ) {
            const int gr = tid >> 5, gl = tid & 31;
            const int idx = x[(size_t)(t + 1) * BATCH + row0 + gr];
            if (gl < EMB / 4)
                ((float4*)&u[gr][0])[gl] = ((const float4*)(emb + (size_t)idx * EMB))[gl];
        }
        __syncthreads();   // h_{t+1} + xe_{t+1} visible
    }

    // h1 = relu(h @ W1^T + b1): 16 x 256, cols 4c..4c+3 (exact partition)
    {
        const int j0 = 4 * c;
        float a0[4], a1[4];
#pragma unroll
        for (int d = 0; d < 4; ++d) { a0[d] = b1[j0 + d]; a1[d] = b1[j0 + d]; }
        const float4* w[4];
#pragma unroll
        for (int d = 0; d < 4; ++d) w[d] = (const float4*)(W1 + (size_t)(j0 + d) * HID);
        const float4* ua = (const float4*)&u[r0][EMB];
        const float4* ub = (const float4*)&u[r1][EMB];
        for (int kk = 0; kk < HID / 4; ++kk) {
            const float4 a = ua[kk], b = ub[kk];
#pragma unroll
            for (int d = 0; d < 4; ++d) {
                const float4 ww = w[d][kk];
                fma4(a0[d], a, ww);
                fma4(a1[d], b, ww);
            }
        }
#pragma unroll
        for (int d = 0; d < 4; ++d) {
            h1s[r0][j0 + d] = fmaxf(a0[d], 0.0f);
            h1s[r1][j0 + d] = fmaxf(a1[d], 0.0f);
        }
    }
    __syncthreads();

    // out = h1 @ W2^T + b2: 16 x 2, one wave does it
    if (tid < 32) {
        const int r = tid & 15, o = tid >> 4;
        float a = b2[o];
        const float* w = W2 + (size_t)o * NH1;
        for (int k = 0; k < NH1; ++k) a += h1s[r][k] * w[k];
        out[(size_t)(row0 + r) * 2 + o] = a;
    }
}

extern "C" void kernel_launch(void* const* d_in, const int* in_sizes, int n_in,
                              void* d_out, int out_size, void* d_ws, size_t ws_size,
                              hipStream_t stream) {
    const int*   x    = (const int*)d_in[0];
    const float* emb  = (const float*)d_in[1];
    const float* W_ih = (const float*)d_in[2];
    const float* b_ih = (const float*)d_in[3];
    const float* W_hh = (const float*)d_in[4];
    const float* b_hh = (const float*)d_in[5];
    const float* W1   = (const float*)d_in[6];
    const float* b1   = (const float*)d_in[7];
    const float* W2   = (const float*)d_in[8];
    const float* b2   = (const float*)d_in[9];
    float* outp = (float*)d_out;

    hipLaunchKernelGGL(rnn_fused, dim3(BATCH / BM), dim3(512), 0, stream,
                       x, emb, W_ih, b_ih, W_hh, b_hh, W1, b1, W2, b2, outp);
}

// Round 2
// 556.882 us; speedup vs baseline: 10.6532x; 10.6532x over previous
//
#include <hip/hip_runtime.h>

#define SEQ   200
#define BATCH 4096
#define EMB   100
#define HID   300
#define NH1   256
#define BM    16
#define HOFF  112            // h starts at half-offset 112 (16B-aligned)
#define UP    440            // halves per u row: 112 + 320 + 8 pad; 880 B, 16B-aligned
#define NFRAG 13             // K = 416 = 13*32 (xe 0..99, zeros 100..111, h 112..411, zeros 412..415)
#define NT    3              // col-tiles per wave; 8 waves * 3 * 16 = 384 cols (300 real)
#define H1P   260

typedef _Float16 half8 __attribute__((ext_vector_type(8)));
typedef _Float16 half4h __attribute__((ext_vector_type(4)));
typedef float floatx4 __attribute__((ext_vector_type(4)));

__device__ __forceinline__ float fast_tanh(float x) {
    float e = __expf(-2.0f * x);
    return (1.0f - e) / (1.0f + e);
}

__global__ void __launch_bounds__(512, 2)
rnn_fused(const int* __restrict__ x, const float* __restrict__ emb,
          const float* __restrict__ W_ih, const float* __restrict__ b_ih,
          const float* __restrict__ W_hh, const float* __restrict__ b_hh,
          const float* __restrict__ W1, const float* __restrict__ b1,
          const float* __restrict__ W2, const float* __restrict__ b2,
          float* __restrict__ out)
{
    __shared__ _Float16 u[BM][UP];       // [xe(100)|pad|h(300)|pad] fp16
    __shared__ int      xs[SEQ * BM];    // all token indices for this block
    __shared__ float    h1s[BM][H1P];

    const int tid  = threadIdx.x;
    const int lane = tid & 63;
    const int w    = tid >> 6;           // wave id 0..7
    const int ln15 = lane & 15;
    const int q    = lane >> 4;          // 0..3
    const int row0 = blockIdx.x * BM;

    // zero u (16*440 halves = 3520 words)
    for (int i = tid; i < BM * UP / 2; i += 512) ((unsigned int*)u)[i] = 0u;
    // stage all x indices for this block: 200*16 ints
    for (int i = tid; i < SEQ * BM; i += 512)
        xs[i] = x[(size_t)(i >> 4) * BATCH + row0 + (i & 15)];

    // ---- W fragments in registers: B[n][k] with n = (3w+tt)*16 + ln15, k = kk*32 + q*8 + j
    half8  Wb[NT][NFRAG];
    float  biasv[NT];
#pragma unroll
    for (int tt = 0; tt < NT; ++tt) {
        const int n = (3 * w + tt) * 16 + ln15;
        biasv[tt] = (n < HID) ? (b_ih[n] + b_hh[n]) : 0.0f;
#pragma unroll
        for (int kk = 0; kk < NFRAG; ++kk) {
            half8 hv;
#pragma unroll
            for (int j = 0; j < 8; ++j) {
                const int k = kk * 32 + q * 8 + j;
                float v = 0.0f;
                if (n < HID) {
                    if (k < EMB)                      v = W_ih[n * EMB + k];
                    else if (k >= HOFF && k < HOFF + HID) v = W_hh[n * HID + (k - HOFF)];
                }
                hv[j] = (_Float16)v;
            }
            Wb[tt][kk] = hv;
        }
    }
    __syncthreads();

    // xe for t=0: 16 rows x 25 float4, threads 0..399
    const int gr = tid / 25, gc = tid - gr * 25;   // row, float4-chunk
    if (tid < 400) {
        const int idx = xs[gr];
        const float4 f = ((const float4*)emb)[(size_t)idx * 25 + gc];
        half4h hv; hv[0] = (_Float16)f.x; hv[1] = (_Float16)f.y;
                   hv[2] = (_Float16)f.z; hv[3] = (_Float16)f.w;
        *(half4h*)&u[gr][gc * 4] = hv;
    }
    __syncthreads();

    for (int t = 0; t < SEQ; ++t) {
        floatx4 acc[NT];
#pragma unroll
        for (int tt = 0; tt < NT; ++tt) {
            const float b = biasv[tt];
            acc[tt][0] = b; acc[tt][1] = b; acc[tt][2] = b; acc[tt][3] = b;
        }
        // K loop: per-frag LDS load of A (shared across 3 tiles)
#pragma unroll
        for (int kk = 0; kk < NFRAG; ++kk) {
            const half8 a = *(const half8*)&u[ln15][kk * 32 + q * 8];
#pragma unroll
            for (int tt = 0; tt < NT; ++tt)
                acc[tt] = __builtin_amdgcn_mfma_f32_16x16x32_f16(a, Wb[tt][kk], acc[tt], 0, 0, 0);
        }
        // prefetch xe_{t+1}
        float4 pf;
        const bool do_pf = (t + 1 < SEQ) && (tid < 400);
        if (do_pf) {
            const int idx = xs[(t + 1) * BM + gr];
            pf = ((const float4*)emb)[(size_t)idx * 25 + gc];
        }
        __syncthreads();   // all reads of u for step t complete

        // tanh + write h_{t+1} (C/D layout: row = q*4 + r, col = tile*16 + ln15)
#pragma unroll
        for (int tt = 0; tt < NT; ++tt) {
            const int n = (3 * w + tt) * 16 + ln15;
            if (n < HID) {
#pragma unroll
                for (int r = 0; r < 4; ++r)
                    u[q * 4 + r][HOFF + n] = (_Float16)fast_tanh(acc[tt][r]);
            }
        }
        if (do_pf) {
            half4h hv; hv[0] = (_Float16)pf.x; hv[1] = (_Float16)pf.y;
                       hv[2] = (_Float16)pf.z; hv[3] = (_Float16)pf.w;
            *(half4h*)&u[gr][gc * 4] = hv;
        }
        __syncthreads();   // h_{t+1} + xe_{t+1} visible
    }

    // ---- head: h1 = relu(h @ W1^T + b1), 16x256, 16 tiles over 8 waves (2 each), K=320 (10 frags)
    {
        floatx4 hacc[2];
        int ncol[2];
#pragma unroll
        for (int tt = 0; tt < 2; ++tt) {
            const int n = (w * 2 + tt) * 16 + ln15;
            ncol[tt] = n;
            const float b = b1[n];
            hacc[tt][0] = b; hacc[tt][1] = b; hacc[tt][2] = b; hacc[tt][3] = b;
        }
#pragma unroll
        for (int kk = 0; kk < 10; ++kk) {
            const half8 a = *(const half8*)&u[ln15][HOFF + kk * 32 + q * 8];
#pragma unroll
            for (int tt = 0; tt < 2; ++tt) {
                half8 bv;
#pragma unroll
                for (int j = 0; j < 8; ++j) {
                    const int k = kk * 32 + q * 8 + j;
                    bv[j] = (_Float16)((k < HID) ? W1[ncol[tt] * HID + k] : 0.0f);
                }
                hacc[tt] = __builtin_amdgcn_mfma_f32_16x16x32_f16(a, bv, hacc[tt], 0, 0, 0);
            }
        }
#pragma unroll
        for (int tt = 0; tt < 2; ++tt)
#pragma unroll
            for (int r = 0; r < 4; ++r)
                h1s[q * 4 + r][ncol[tt]] = fmaxf(hacc[tt][r], 0.0f);
    }
    __syncthreads();

    // ---- out = h1 @ W2^T + b2: 16 rows x 2 cols
    if (tid < 32) {
        const int r = tid & 15, o = tid >> 4;
        float a = b2[o];
        const float* ww = W2 + (size_t)o * NH1;
        for (int k = 0; k < NH1; ++k) a += h1s[r][k] * ww[k];
        out[(size_t)(row0 + r) * 2 + o] = a;
    }
}

extern "C" void kernel_launch(void* const* d_in, const int* in_sizes, int n_in,
                              void* d_out, int out_size, void* d_ws, size_t ws_size,
                              hipStream_t stream) {
    const int*   x    = (const int*)d_in[0];
    const float* emb  = (const float*)d_in[1];
    const float* W_ih = (const float*)d_in[2];
    const float* b_ih = (const float*)d_in[3];
    const float* W_hh = (const float*)d_in[4];
    const float* b_hh = (const float*)d_in[5];
    const float* W1   = (const float*)d_in[6];
    const float* b1   = (const float*)d_in[7];
    const float* W2   = (const float*)d_in[8];
    const float* b2   = (const float*)d_in[9];
    float* outp = (float*)d_out;

    hipLaunchKernelGGL(rnn_fused, dim3(BATCH / BM), dim3(512), 0, stream,
                       x, emb, W_ih, b_ih, W_hh, b_hh, W1, b1, W2, b2, outp);
}

// Round 3
// 429.011 us; speedup vs baseline: 13.8285x; 1.2981x over previous
//
#include <hip/hip_runtime.h>

#define SEQ   200
#define BATCH 4096
#define EMB   100
#define HID   300
#define NH1   256
#define BM    16
#define HOFF  112            // h starts at half-offset 112 (16B-aligned)
#define UP    440            // halves per u row: 112 + 320 + 8 pad; 880 B, 16B-aligned
#define NFRAG 13             // K = 416 = 13*32 (xe 0..99, zeros 100..111, h 112..411, zeros)
#define NT    3              // col-tiles per wave; 8 waves * 3 * 16 = 384 cols (300 real)
#define H1P   260

typedef _Float16 half8 __attribute__((ext_vector_type(8)));
typedef _Float16 half4h __attribute__((ext_vector_type(4)));
typedef float floatx4 __attribute__((ext_vector_type(4)));

__device__ __forceinline__ float fast_tanh(float x) {
    // tanh(x) = 1 - 2/(e^{2x}+1); v_exp path + v_rcp, ~5 VALU ops
    float e = __expf(2.0f * x);
    float r = __builtin_amdgcn_rcpf(e + 1.0f);
    return 1.0f - 2.0f * r;
}

__global__ void __launch_bounds__(512)
rnn_fused(const int* __restrict__ x, const float* __restrict__ emb,
          const float* __restrict__ W_ih, const float* __restrict__ b_ih,
          const float* __restrict__ W_hh, const float* __restrict__ b_hh,
          const float* __restrict__ W1, const float* __restrict__ b1,
          const float* __restrict__ W2, const float* __restrict__ b2,
          float* __restrict__ out)
{
    __shared__ _Float16 u[2][BM][UP];    // double-buffered [xe(100)|pad|h(300)|pad] fp16
    __shared__ int      xs[SEQ * BM];    // all token indices for this block
    __shared__ float    h1s[BM][H1P];

    const int tid  = threadIdx.x;
    const int lane = tid & 63;
    const int w    = tid >> 6;           // wave id 0..7
    const int ln15 = lane & 15;
    const int q    = lane >> 4;          // 0..3
    const int row0 = blockIdx.x * BM;

    // zero both u buffers
    for (int i = tid; i < 2 * BM * UP / 2; i += 512) ((unsigned int*)u)[i] = 0u;
    // stage all x indices for this block: 200*16 ints
    for (int i = tid; i < SEQ * BM; i += 512)
        xs[i] = x[(size_t)(i >> 4) * BATCH + row0 + (i & 15)];

    // ---- W fragments in registers: B[n][k], n = (3w+tt)*16 + ln15, k = kk*32 + q*8 + j
    half8  Wb[NT][NFRAG];
    float  biasv[NT];
#pragma unroll
    for (int tt = 0; tt < NT; ++tt) {
        const int n = (3 * w + tt) * 16 + ln15;
        biasv[tt] = (n < HID) ? (b_ih[n] + b_hh[n]) : 0.0f;
#pragma unroll
        for (int kk = 0; kk < NFRAG; ++kk) {
            union { half8 h; unsigned int d[4]; } cv;
#pragma unroll
            for (int j = 0; j < 8; ++j) {
                const int k = kk * 32 + q * 8 + j;
                float v = 0.0f;
                if (n < HID) {
                    if (k < EMB)                          v = W_ih[n * EMB + k];
                    else if (k >= HOFF && k < HOFF + HID) v = W_hh[n * HID + (k - HOFF)];
                }
                cv.h[j] = (_Float16)v;
            }
            // pin: make the values non-rematerializable so RA keeps them resident
            asm volatile("" : "+v"(cv.d[0]), "+v"(cv.d[1]), "+v"(cv.d[2]), "+v"(cv.d[3]));
            Wb[tt][kk] = cv.h;
        }
    }
    __syncthreads();

    // xe for t=0 into u[0]: 16 rows x 25 float4, threads 0..399
    const int gr = tid / 25, gc = tid - gr * 25;
    if (tid < 400) {
        const int idx = xs[gr];
        const float4 f = ((const float4*)emb)[(size_t)idx * 25 + gc];
        half4h hv; hv[0] = (_Float16)f.x; hv[1] = (_Float16)f.y;
                   hv[2] = (_Float16)f.z; hv[3] = (_Float16)f.w;
        *(half4h*)&u[0][gr][gc * 4] = hv;
    }
    __syncthreads();

    for (int t = 0; t < SEQ; ++t) {
        const int p = t & 1;
        _Float16 (*cur)[UP] = u[p];
        _Float16 (*nxt)[UP] = u[1 - p];

        // issue xe_{t+1} gather FIRST — latency hides under the MFMA phase
        float4 pf;
        const bool do_pf = (t + 1 < SEQ) && (tid < 400);
        if (do_pf) {
            const int idx = xs[(t + 1) * BM + gr];
            pf = ((const float4*)emb)[(size_t)idx * 25 + gc];
        }

        floatx4 acc[NT];
#pragma unroll
        for (int tt = 0; tt < NT; ++tt) {
            const float b = biasv[tt];
            acc[tt][0] = b; acc[tt][1] = b; acc[tt][2] = b; acc[tt][3] = b;
        }
#pragma unroll
        for (int kk = 0; kk < NFRAG; ++kk) {
            const half8 a = *(const half8*)&cur[ln15][kk * 32 + q * 8];
#pragma unroll
            for (int tt = 0; tt < NT; ++tt)
                acc[tt] = __builtin_amdgcn_mfma_f32_16x16x32_f16(a, Wb[tt][kk], acc[tt], 0, 0, 0);
        }

        // write xe_{t+1} into nxt (vmcnt wait lands here, after MFMA issue)
        if (do_pf) {
            half4h hv; hv[0] = (_Float16)pf.x; hv[1] = (_Float16)pf.y;
                       hv[2] = (_Float16)pf.z; hv[3] = (_Float16)pf.w;
            *(half4h*)&nxt[gr][gc * 4] = hv;
        }
        // tanh + write h_{t+1} into nxt (C/D layout: row = q*4 + r, col = tile*16 + ln15)
#pragma unroll
        for (int tt = 0; tt < NT; ++tt) {
            const int n = (3 * w + tt) * 16 + ln15;
            if (n < HID) {
#pragma unroll
                for (int r = 0; r < 4; ++r)
                    nxt[q * 4 + r][HOFF + n] = (_Float16)fast_tanh(acc[tt][r]);
            }
        }
        __syncthreads();   // single barrier per step
    }

    // ---- head: h1 = relu(h @ W1^T + b1); final h lives in u[SEQ & 1] == u[0]
    {
        _Float16 (*hf)[UP] = u[SEQ & 1];
        floatx4 hacc[2];
        int ncol[2];
#pragma unroll
        for (int tt = 0; tt < 2; ++tt) {
            const int n = (w * 2 + tt) * 16 + ln15;
            ncol[tt] = n;
            const float b = b1[n];
            hacc[tt][0] = b; hacc[tt][1] = b; hacc[tt][2] = b; hacc[tt][3] = b;
        }
#pragma unroll
        for (int kk = 0; kk < 10; ++kk) {
            const half8 a = *(const half8*)&hf[ln15][HOFF + kk * 32 + q * 8];
#pragma unroll
            for (int tt = 0; tt < 2; ++tt) {
                half8 bv;
#pragma unroll
                for (int j = 0; j < 8; ++j) {
                    const int k = kk * 32 + q * 8 + j;
                    bv[j] = (_Float16)((k < HID) ? W1[ncol[tt] * HID + k] : 0.0f);
                }
                hacc[tt] = __builtin_amdgcn_mfma_f32_16x16x32_f16(a, bv, hacc[tt], 0, 0, 0);
            }
        }
#pragma unroll
        for (int tt = 0; tt < 2; ++tt)
#pragma unroll
            for (int r = 0; r < 4; ++r)
                h1s[q * 4 + r][ncol[tt]] = fmaxf(hacc[tt][r], 0.0f);
    }
    __syncthreads();

    // ---- out = h1 @ W2^T + b2: 16 rows x 2 cols
    if (tid < 32) {
        const int r = tid & 15, o = tid >> 4;
        float a = b2[o];
        const float* ww = W2 + (size_t)o * NH1;
        for (int k = 0; k < NH1; ++k) a += h1s[r][k] * ww[k];
        out[(size_t)(row0 + r) * 2 + o] = a;
    }
}

extern "C" void kernel_launch(void* const* d_in, const int* in_sizes, int n_in,
                              void* d_out, int out_size, void* d_ws, size_t ws_size,
                              hipStream_t stream) {
    const int*   x    = (const int*)d_in[0];
    const float* emb  = (const float*)d_in[1];
    const float* W_ih = (const float*)d_in[2];
    const float* b_ih = (const float*)d_in[3];
    const float* W_hh = (const float*)d_in[4];
    const float* b_hh = (const float*)d_in[5];
    const float* W1   = (const float*)d_in[6];
    const float* b1   = (const float*)d_in[7];
    const float* W2   = (const float*)d_in[8];
    const float* b2   = (const float*)d_in[9];
    float* outp = (float*)d_out;

    hipLaunchKernelGGL(rnn_fused, dim3(BATCH / BM), dim3(512), 0, stream,
                       x, emb, W_ih, b_ih, W_hh, b_hh, W1, b1, W2, b2, outp);
}